// Round 4
// baseline (266.331 us; speedup 1.0000x reference)
//
#include <hip/hip_runtime.h>

typedef unsigned short u16;
typedef __attribute__((ext_vector_type(8))) short bf16x8;
typedef __attribute__((ext_vector_type(4))) float f32x4;

#define LOG2E 1.4426950408889634f

__device__ __forceinline__ float bf2f(u16 v) {
    union { unsigned u; float f; } x; x.u = ((unsigned)v) << 16; return x.f;
}
__device__ __forceinline__ u16 f2bf(float f) {
    union { float f; unsigned u; } x; x.f = f;
    unsigned u = x.u;
    u += 0x7FFFu + ((u >> 16) & 1u);   // round-to-nearest-even
    return (u16)(u >> 16);
}

// ---------------------------------------------------------------------------
// K1: time-kernel attention + cross projection. Inputs fp32.
// grid: 256 blocks = 8 b * 32 q-tiles(4), 256 threads (thread = channel d)
// ---------------------------------------------------------------------------
__global__ __launch_bounds__(256)
void k1_attn_cross(const float* __restrict__ x, const float* __restrict__ ts,
                   const float* __restrict__ qy, const float* __restrict__ bww,
                   const float* __restrict__ cw, const float* __restrict__ cb,
                   u16* __restrict__ outb)
{
    const int blk = blockIdx.x;
    const int b  = blk >> 5;
    const int q0 = (blk & 31) * 4;
    const int d  = threadIdx.x;
    const int dm = 128 + (d & 127);

    __shared__ __align__(16) float sc[4][512];
    __shared__ __align__(16) float xs[2][2048];   // 8 rows of 256 f32, dbuf
    __shared__ __align__(16) float attn[4][256];

    for (int i = d; i < 4 * 512; i += 256) {
        int qq = i >> 9, s = i & 511;
        float diff = qy[q0 + qq] - ts[b * 512 + s];
        sc[qq][s] = -diff * diff;
    }
    float w  = bww[d];
    float kk = log1pf(expf(w)) * LOG2E;   // exp(sc*bw) == exp2(sc*kk)

    const float* xb = x + (size_t)b * 512 * 256;
    *(float4*)&xs[0][d * 8]     = *(const float4*)&xb[d * 8];
    *(float4*)&xs[0][d * 8 + 4] = *(const float4*)&xb[d * 8 + 4];
    __syncthreads();

    float num[4] = {0.f, 0.f, 0.f, 0.f}, den[4] = {0.f, 0.f, 0.f, 0.f};
    for (int s0 = 0; s0 < 512; s0 += 8) {
        int cur = (s0 >> 3) & 1;
        if (s0 + 8 < 512) {
            const float* src = &xb[(s0 + 8) * 256 + d * 8];
            *(float4*)&xs[cur ^ 1][d * 8]     = *(const float4*)&src[0];
            *(float4*)&xs[cur ^ 1][d * 8 + 4] = *(const float4*)&src[4];
        }
        #pragma unroll
        for (int ss = 0; ss < 8; ss++) {
            float xv  = xs[cur][ss * 256 + d];
            float mv  = xs[cur][ss * 256 + dm];   // mask in {0,1}
            float mxv = mv * xv;
            #pragma unroll
            for (int qq = 0; qq < 4; qq++) {
                float p = exp2f(sc[qq][s0 + ss] * kk);
                num[qq] += p * mxv;
                den[qq] += p * mv;
            }
        }
        __syncthreads();
    }
    #pragma unroll
    for (int qq = 0; qq < 4; qq++)
        attn[qq][d] = num[qq] / fmaxf(den[qq], 1e-30f);
    __syncthreads();

    float cbv = cb[d];
    float acc[4] = {cbv, cbv, cbv, cbv};
    const float* wr = cw + (size_t)d * 256;
    for (int k0 = 0; k0 < 256; k0 += 4) {
        float4 wv = *(const float4*)&wr[k0];
        float4 a0 = *(const float4*)&attn[0][k0];
        float4 a1 = *(const float4*)&attn[1][k0];
        float4 a2 = *(const float4*)&attn[2][k0];
        float4 a3 = *(const float4*)&attn[3][k0];
        acc[0] += wv.x * a0.x + wv.y * a0.y + wv.z * a0.z + wv.w * a0.w;
        acc[1] += wv.x * a1.x + wv.y * a1.y + wv.z * a1.z + wv.w * a1.w;
        acc[2] += wv.x * a2.x + wv.y * a2.y + wv.z * a2.z + wv.w * a2.w;
        acc[3] += wv.x * a3.x + wv.y * a3.y + wv.z * a3.z + wv.w * a3.w;
    }
    #pragma unroll
    for (int qq = 0; qq < 4; qq++)
        outb[(size_t)(b * 128 + q0 + qq) * 256 + d] = f2bf(acc[qq]);
}

// ---------------------------------------------------------------------------
// K2: xp[z] = outb @ w_ih_z^T + b_ih_z   via MFMA 16x16x32 bf16.
// outb is bf16 (ours); w_ih fp32 -> converted to bf16 fragments on the fly.
// 64 r-tiles x 24 n-tiles x 2 dirs = 3072 wave-tiles; 4 waves/block.
// ---------------------------------------------------------------------------
__global__ __launch_bounds__(256)
void k2_xp(const u16* __restrict__ outb,
           const float* __restrict__ wf, const float* __restrict__ bf_,
           const float* __restrict__ wb, const float* __restrict__ bb_,
           u16* __restrict__ xp)     // [2][1024][384] bf16
{
    const int wid  = threadIdx.x >> 6;
    const int lane = threadIdx.x & 63;
    int gw = blockIdx.x * 4 + wid;           // 0..3071
    int z  = (gw >= 1536) ? 1 : 0;
    int t  = gw - z * 1536;
    int rt = t / 24, nt = t - rt * 24;
    int r0 = rt * 16, n0 = nt * 16;

    const float* W  = z ? wb  : wf;
    const float* Bv = z ? bb_ : bf_;

    const u16*   arow = outb + (size_t)(r0 + (lane & 15)) * 256 + (lane >> 4) * 8;
    const float* brow = W    + (size_t)(n0 + (lane & 15)) * 256 + (lane >> 4) * 8;

    f32x4 acc = {0.f, 0.f, 0.f, 0.f};
    #pragma unroll
    for (int k = 0; k < 8; k++) {
        bf16x8 a = *(const bf16x8*)(arow + k * 32);
        float4 w0 = *(const float4*)(brow + k * 32);
        float4 w1 = *(const float4*)(brow + k * 32 + 4);
        bf16x8 bfrag;
        bfrag[0] = (short)f2bf(w0.x); bfrag[1] = (short)f2bf(w0.y);
        bfrag[2] = (short)f2bf(w0.z); bfrag[3] = (short)f2bf(w0.w);
        bfrag[4] = (short)f2bf(w1.x); bfrag[5] = (short)f2bf(w1.y);
        bfrag[6] = (short)f2bf(w1.z); bfrag[7] = (short)f2bf(w1.w);
        acc = __builtin_amdgcn_mfma_f32_16x16x32_bf16(a, bfrag, acc, 0, 0, 0);
    }
    int col   = n0 + (lane & 15);
    int rbase = r0 + (lane >> 4) * 4;
    float bias = Bv[col];
    u16* xpz = xp + (size_t)z * 1024 * 384;
    #pragma unroll
    for (int i = 0; i < 4; i++)
        xpz[(size_t)(rbase + i) * 384 + col] = f2bf(acc[i] + bias);
}

// ---------------------------------------------------------------------------
// K3: bidirectional GRU, 16 blocks = (b, dir), 384 threads (thread = gate dim)
// w_hh fp32 in VGPRs; h fp32 in LDS; hout bf16 (aliases dead outb region).
// ---------------------------------------------------------------------------
__global__ __launch_bounds__(384)
void k3_gru(const u16* __restrict__ xp,       // [2][1024][384] bf16
            const float* __restrict__ whf, const float* __restrict__ bhf,
            const float* __restrict__ whb, const float* __restrict__ bhb,
            u16* __restrict__ hout)           // [2][8][128][128] bf16
{
    const int z = blockIdx.x & 1;
    const int b = blockIdx.x >> 1;
    const int d = threadIdx.x;                // 0..383

    const float* W  = z ? whb : whf;
    const float* bh = z ? bhb : bhf;

    float w[128];
    #pragma unroll
    for (int k0 = 0; k0 < 128; k0 += 4)
        *(float4*)&w[k0] = *(const float4*)&W[(size_t)d * 128 + k0];
    float bias = bh[d];

    __shared__ __align__(16) float h[128];
    __shared__ float hp[384];
    __shared__ float xg[384];
    if (d < 128) h[d] = 0.f;
    __syncthreads();

    const u16* xpz = xp + (size_t)z * 1024 * 384 + (size_t)b * 128 * 384;
    u16* ho = hout + (size_t)z * 8 * 128 * 128 + (size_t)b * 128 * 128;

    for (int i = 0; i < 128; i++) {
        int t = z ? (127 - i) : i;
        float xv = bf2f(xpz[(size_t)t * 384 + d]);
        float a0 = 0.f, a1 = 0.f, a2 = 0.f, a3 = 0.f;
        #pragma unroll
        for (int k0 = 0; k0 < 128; k0 += 16) {
            float4 h0 = *(const float4*)&h[k0];
            float4 h1 = *(const float4*)&h[k0 + 4];
            float4 h2 = *(const float4*)&h[k0 + 8];
            float4 h3 = *(const float4*)&h[k0 + 12];
            a0 += w[k0]      * h0.x + w[k0 + 1]  * h0.y + w[k0 + 2]  * h0.z + w[k0 + 3]  * h0.w;
            a1 += w[k0 + 4]  * h1.x + w[k0 + 5]  * h1.y + w[k0 + 6]  * h1.z + w[k0 + 7]  * h1.w;
            a2 += w[k0 + 8]  * h2.x + w[k0 + 9]  * h2.y + w[k0 + 10] * h2.z + w[k0 + 11] * h2.w;
            a3 += w[k0 + 12] * h3.x + w[k0 + 13] * h3.y + w[k0 + 14] * h3.z + w[k0 + 15] * h3.w;
        }
        hp[d] = bias + ((a0 + a1) + (a2 + a3));
        xg[d] = xv;
        __syncthreads();
        if (d < 128) {
            float r  = 1.f / (1.f + exp2f(-(xg[d] + hp[d]) * LOG2E));
            float zz = 1.f / (1.f + exp2f(-(xg[d + 128] + hp[d + 128]) * LOG2E));
            float nn = xg[d + 256] + r * hp[d + 256];
            float e  = exp2f(nn * (2.f * LOG2E));
            float th = 1.f - 2.f / (e + 1.f);          // tanh, saturates safely
            float hn = (1.f - zz) * th + zz * h[d];
            h[d] = hn;
            ho[(size_t)t * 128 + d] = f2bf(hn);
        }
        __syncthreads();
    }
}

// ---------------------------------------------------------------------------
// K4: MLP head. 1024 blocks = (b,t), 128 threads. Weights fp32, OUTPUT fp32.
// ---------------------------------------------------------------------------
__global__ __launch_bounds__(128)
void k4_mlp(const u16* __restrict__ hout,     // [2][8][128][128] bf16
            const float* __restrict__ w1, const float* __restrict__ b1,
            const float* __restrict__ w2, const float* __restrict__ b2,
            float* __restrict__ out)          // [1024][64] fp32
{
    const int bq  = blockIdx.x;
    const int tid = threadIdx.x;

    __shared__ __align__(16) float hrow[256];
    __shared__ float hid[50];

    const u16* hf = hout + (size_t)bq * 128;
    const u16* hb = hout + (size_t)8 * 128 * 128 + (size_t)bq * 128;
    hrow[tid]       = bf2f(hf[tid]);
    hrow[128 + tid] = bf2f(hb[tid]);
    __syncthreads();

    if (tid < 50) {
        float a = b1[tid];
        const float* wr = w1 + (size_t)tid * 256;
        for (int k0 = 0; k0 < 256; k0 += 8) {
            float4 wv0 = *(const float4*)&wr[k0];
            float4 wv1 = *(const float4*)&wr[k0 + 4];
            float4 h0  = *(const float4*)&hrow[k0];
            float4 h1  = *(const float4*)&hrow[k0 + 4];
            a += wv0.x * h0.x + wv0.y * h0.y + wv0.z * h0.z + wv0.w * h0.w;
            a += wv1.x * h1.x + wv1.y * h1.y + wv1.z * h1.z + wv1.w * h1.w;
        }
        hid[tid] = fmaxf(a, 0.f);
    }
    __syncthreads();
    if (tid < 64) {
        float a = b2[tid];
        const float* wr = w2 + (size_t)tid * 50;
        for (int k = 0; k < 50; k++) a += wr[k] * hid[k];
        out[(size_t)bq * 64 + tid] = a;
    }
}

// ---------------------------------------------------------------------------
// Workspace layout (2.0 MB total):
//   [0,     512K) : outb (bf16, K1 out / K2 in) -- reused as hout by K3/K4
//   [512K,  2.0M) : xp   (bf16, K2 out / K3 in)
// hout aliases outb: outb dead after K2; K3 reads only xp while writing hout.
// ---------------------------------------------------------------------------
extern "C" void kernel_launch(void* const* d_in, const int* in_sizes, int n_in,
                              void* d_out, int out_size, void* d_ws, size_t ws_size,
                              hipStream_t stream)
{
    const float* x    = (const float*)d_in[0];
    const float* ts   = (const float*)d_in[1];
    const float* qy   = (const float*)d_in[2];
    const float* bww  = (const float*)d_in[3];
    const float* cw   = (const float*)d_in[4];
    const float* cb   = (const float*)d_in[5];
    const float* wihf = (const float*)d_in[6];
    const float* whhf = (const float*)d_in[7];
    const float* bihf = (const float*)d_in[8];
    const float* bhhf = (const float*)d_in[9];
    const float* wihb = (const float*)d_in[10];
    const float* whhb = (const float*)d_in[11];
    const float* bihb = (const float*)d_in[12];
    const float* bhhb = (const float*)d_in[13];
    const float* w1   = (const float*)d_in[14];
    const float* b1   = (const float*)d_in[15];
    const float* w2   = (const float*)d_in[16];
    const float* b2   = (const float*)d_in[17];
    float* out = (float*)d_out;

    char* ws = (char*)d_ws;
    u16* outb = (u16*)ws;                     // 512 KB (1024x256 bf16)
    u16* hout = (u16*)ws;                     // alias: 512 KB (2x8x128x128 bf16)
    u16* xp   = (u16*)(ws + 512 * 1024);      // 1.5 MB (2x1024x384 bf16)

    k1_attn_cross<<<256, 256, 0, stream>>>(x, ts, qy, bww, cw, cb, outb);
    k2_xp<<<768, 256, 0, stream>>>(outb, wihf, bihf, wihb, bihb, xp);
    k3_gru<<<16, 384, 0, stream>>>(xp, whhf, bhhf, whhb, bhhb, hout);
    k4_mlp<<<1024, 128, 0, stream>>>(hout, w1, b1, w2, b2, out);
}